// Round 3
// baseline (238.734 us; speedup 1.0000x reference)
//
#include <hip/hip_runtime.h>

// Newton-Schulz batched inverse, 1024 x (128x128) fp32.
// R9: value-preserving perf pass on the verified R6 kernel (bit-identical
// trajectory; the R7/R8 tr-read restructure failed accuracy and is dropped).
//  - W fragments in registers (bf16(stage), identical bits to R6's wrm)
//    -> wrm buffer + 8 of 16 mm1 b128 reads/iter deleted
//  - XOR swizzle widened R&7 -> R&15: all strided b128 LDS reads/writes go
//    4-way -> 2-way bank conflict (2-way is free, m136)
//  - mm2 B-operand (xrm rows) prefetched during mm1 (xrm stable there)
//  - LDS 128KB; 1024 thr / 16 waves / 1 block/CU; 3 barriers/iter.

#define NN 128

typedef __attribute__((ext_vector_type(8))) short bf16x8;
typedef __attribute__((ext_vector_type(16))) float f32x16;
typedef __attribute__((ext_vector_type(4))) float f32x4;
typedef __attribute__((ext_vector_type(4))) unsigned short us4;

// LDS layout (bytes):
#define XRM_OFF   0        // X row-major bf16                 32768
#define XCM_OFF   32768    // X col-major bf16                 32768
#define SCR_OFF   65536    // T col-major bf16                 32768
#define STAGE_OFF 65536    // fp32 W stage 65536 = [65536,131072); dead before scr use
#define RED_OFF   0        // 256 floats in xrm region during phase 0 only
#define LDS_BYTES 131072

__device__ __forceinline__ unsigned short f2bf(float f) {
  unsigned u = __float_as_uint(f);
  return (unsigned short)((u + 0x7FFFu + ((u >> 16) & 1u)) >> 16);  // RNE
}
__device__ __forceinline__ float bf2f(unsigned short h) {
  return __uint_as_float(((unsigned)h) << 16);
}
__device__ __forceinline__ f32x16 zero16() {
  f32x16 z;
#pragma unroll
  for (int i = 0; i < 16; ++i) z[i] = 0.0f;
  return z;
}
// XOR swizzle in a [R][128] bf16 buffer: 8-elem granule g -> g ^ (R&15).
// (4-bit XOR: lanes reading 32 consecutive rows at one column hit 16
// distinct granules -> 2 lanes/bank -> conflict-free; R6's 3-bit was 4-way.)
__device__ __forceinline__ int swz8(int R, int k0) {  // k0 % 8 == 0
  return R * 128 + (((k0 >> 3) ^ (R & 15)) << 3);
}
__device__ __forceinline__ int swz4(int R, int c0) {  // c0 % 4 == 0
  return R * 128 + ((((c0 >> 3) ^ (R & 15)) << 3) | (c0 & 7));
}
__device__ __forceinline__ int swz1(int R, int c) {
  return R * 128 + ((((c >> 3) ^ (R & 15)) << 3) | (c & 7));
}

__global__ void __launch_bounds__(1024)
ns_inverse_kernel(const float* __restrict__ Wglob, const int* __restrict__ nIt,
                  float* __restrict__ outglob) {
  extern __shared__ char lds[];
  unsigned short* xrm = (unsigned short*)(lds + XRM_OFF);
  unsigned short* xcm = (unsigned short*)(lds + XCM_OFF);
  unsigned short* scr = (unsigned short*)(lds + SCR_OFF);
  float* stage = (float*)(lds + STAGE_OFF);
  float* red   = (float*)(lds + RED_OFF);

  const int b = blockIdx.x;
  const float* Wg = Wglob + (size_t)b * (NN * NN);
  float* outg = outglob + (size_t)b * (NN * NN);
  const int t = threadIdx.x;      // 0..1023
  const int lane = t & 63;
  const int wv = t >> 6;          // 0..15
  const int l31 = lane & 31;
  const int half = lane >> 5;
  const int s = wv & 3;           // strip: W rows (mm1 A) / X' rows (mm2 B, epi)
  const int v = wv >> 2;          // band: T cols / X' cols (mm2 A, epi)
  const int niters = nIt[0];

  // ---- phase 0: stage W fp32 into LDS (only global read) ----
  {
    const f32x4* src = (const f32x4*)Wg;
    f32x4* dst = (f32x4*)stage;
#pragma unroll
    for (int i = 0; i < 4; ++i) dst[t + 1024 * i] = src[t + 1024 * i];
  }
  __syncthreads();

  // ---- norms (red lives in xrm region; xrm filled later) ----
  if (t < 128) {            // row sums (rotated start)
    float ssum = 0.f;
    for (int jj = 0; jj < NN; ++jj) { int j = (jj + t) & 127; ssum += fabsf(stage[t * NN + j]); }
    red[t] = ssum;
  } else if (t < 256) {     // col sums
    int c = t - 128;
    float ssum = 0.f;
    for (int i = 0; i < NN; ++i) ssum += fabsf(stage[i * NN + c]);
    red[128 + c] = ssum;
  }
  __syncthreads();
  float ninf = 0.f, n1 = 0.f;
  for (int i = 0; i < 128; ++i) {   // broadcast reads (same addr across lanes)
    ninf = fmaxf(ninf, red[i]);
    n1   = fmaxf(n1,   red[128 + i]);
  }
  const float scale = 1.0f / (n1 * ninf);
  __syncthreads();   // everyone has scale; red region may be overwritten now

  // ---- W row fragments to registers (bf16(W), identical to R6's wrm) ----
  const int pX = 32 * s + l31;    // lane-owned W row / X/X' row
  bf16x8 wfrag[8];
#pragma unroll
  for (int ks = 0; ks < 8; ++ks) {
    const float* src = stage + pX * NN + 16 * ks + 8 * half;
    f32x4 f0 = *(const f32x4*)(src);
    f32x4 f1 = *(const f32x4*)(src + 4);
    bf16x8 wb;
#pragma unroll
    for (int e = 0; e < 4; ++e) {
      wb[e]     = (short)f2bf(f0[e]);
      wb[4 + e] = (short)f2bf(f1[e]);
    }
    wfrag[ks] = wb;
  }

  // ---- fills from stage ----
  // xcm row r = X0 col r = W row r * scale
  {
    const int r = t >> 3;
    const int c0 = (t & 7) * 16;
#pragma unroll
    for (int h = 0; h < 4; ++h) {
      f32x4 a = *(const f32x4*)(stage + r * NN + c0 + 4 * h);
      us4 hx;
#pragma unroll
      for (int i = 0; i < 4; ++i) hx[i] = f2bf(a[i] * scale);
      *(us4*)(xcm + swz4(r, c0 + 4 * h)) = hx;
    }
  }
  // xrm row r = X0 row r = W col r * scale (LDS transpose from stage)
  {
    const int r = t & 127;
    const int kc = (t >> 7) * 16;
#pragma unroll
    for (int j4 = 0; j4 < 4; ++j4) {
      int c0 = kc + 4 * j4;
      us4 h4;
#pragma unroll
      for (int i = 0; i < 4; ++i) h4[i] = f2bf(stage[(c0 + i) * NN + r] * scale);
      *(us4*)(xrm + swz4(r, c0)) = h4;
    }
  }
  __syncthreads();   // stage dead from here; scr region free

  // ---------------- iterations: X' = 2X - X(WX) ----------------
  const int rv = 32 * v + l31;    // lane-owned xcm/scr row (= T col = X' col band)
  for (int it = 0; it < niters; ++it) {
    const bool last = (it == niters - 1);

    // ---- mm1: T tile rows [32s..), cols [32v..): A=wfrag (regs), B=xcm ----
    bf16x8 xb[8];   // prefetch of mm2's B operand (xrm rows; stable here)
    {
      f32x16 tt = zero16();
#pragma unroll
      for (int ks = 0; ks < 8; ++ks) {
        int k0 = ks * 16 + half * 8;
        bf16x8 bv = *(const bf16x8*)(xcm + swz8(rv, k0));
        tt = __builtin_amdgcn_mfma_f32_32x32x16_bf16(wfrag[ks], bv, tt, 0, 0, 0);
      }
#pragma unroll
      for (int ks = 0; ks < 8; ++ks) {
        int k0 = ks * 16 + half * 8;
        xb[ks] = *(const bf16x8*)(xrm + swz8(pX, k0));
      }
      // write T tile into scr (T col-major): scr row rv, cols = T rows strip s
#pragma unroll
      for (int q = 0; q < 4; ++q) {
        us4 h4;
#pragma unroll
        for (int i = 0; i < 4; ++i) h4[i] = f2bf(tt[4 * q + i]);
        *(us4*)(scr + swz4(rv, 32 * s + 8 * q + 4 * half)) = h4;
      }
    }
    __syncthreads();   // B1: full T assembled

    // ---- mm2: (X@T)^T tile rows [32v..) (X' cols), cols [32s..) (X' rows) ----
    f32x16 acc = zero16();
#pragma unroll
    for (int ks = 0; ks < 8; ++ks) {
      int k0 = ks * 16 + half * 8;
      bf16x8 av = *(const bf16x8*)(scr + swz8(rv, k0));   // T col-major row
      acc = __builtin_amdgcn_mfma_f32_32x32x16_bf16(av, xb[ks], acc, 0, 0, 0);
    }
    __syncthreads();   // B2: all scr + xrm reads complete before overwrite

    // ---- epilogue: X'[pX][32v + m] = 2X - (X@T) ----
#pragma unroll
    for (int q = 0; q < 4; ++q) {
      int c0m = 32 * v + 8 * q + 4 * half;
      int offr = swz4(pX, c0m);
      us4 xh4 = *(const us4*)(xrm + offr);
      f32x4 vv;
#pragma unroll
      for (int i = 0; i < 4; ++i)
        vv[i] = 2.0f * bf2f(xh4[i]) - acc[4 * q + i];
      if (last) {
        *(f32x4*)(outg + pX * NN + c0m) = vv;
      } else {
        us4 h4;
#pragma unroll
        for (int i = 0; i < 4; ++i) {
          unsigned short hh = f2bf(vv[i]);
          h4[i] = hh;
          xcm[swz1(c0m + i, pX)] = hh;     // X' col-major
        }
        *(us4*)(xrm + offr) = h4;          // X' row-major
      }
    }
    __syncthreads();   // B3: X' committed before next mm1
  }
}

extern "C" void kernel_launch(void* const* d_in, const int* in_sizes, int n_in,
                              void* d_out, int out_size, void* d_ws, size_t ws_size,
                              hipStream_t stream) {
  const float* W = (const float*)d_in[0];
  const int* nIt = (const int*)d_in[1];
  float* out = (float*)d_out;
  const int nmat = in_sizes[0] / (NN * NN);   // 1024

  hipFuncSetAttribute((const void*)ns_inverse_kernel,
                      hipFuncAttributeMaxDynamicSharedMemorySize, LDS_BYTES);
  ns_inverse_kernel<<<nmat, 1024, LDS_BYTES, stream>>>(W, nIt, out);
}

// Round 4
// 210.244 us; speedup vs baseline: 1.1355x; 1.1355x over previous
//
#include <hip/hip_runtime.h>

// Newton-Schulz batched inverse, 1024 x (128x128) fp32.
// R10: R9 with the spill fixed. R9's counters showed VGPR=64 + 184MB
// WRITE_SIZE = compiler capped regs for 8 waves/SIMD and spilled wfrag/xb
// to scratch. __launch_bounds__(1024,4) raises the cap to 128 (we run
// 16 waves = 4/SIMD, 1 block/CU anyway). Also pads the fp32 stage to
// SROW=132 floats so the wfrag init reads are 4-way instead of 32-way
// bank-conflicted. All changes are addressing/allocation only ->
// bit-identical trajectory to R6/R9 (absmax 9.155e-5).
//  - W fragments in registers; wrm buffer + 8 of 16 mm1 b128 reads deleted
//  - mm2 B-operand (xrm rows) prefetched during mm1
//  - LDS 130KB; 1024 thr / 16 waves / 1 block/CU; 3 barriers/iter.

#define NN 128

typedef __attribute__((ext_vector_type(8))) short bf16x8;
typedef __attribute__((ext_vector_type(16))) float f32x16;
typedef __attribute__((ext_vector_type(4))) float f32x4;
typedef __attribute__((ext_vector_type(4))) unsigned short us4;

// LDS layout (bytes):
#define XRM_OFF   0        // X row-major bf16                 32768
#define XCM_OFF   32768    // X col-major bf16                 32768
#define SCR_OFF   65536    // T col-major bf16                 32768
#define STAGE_OFF 65536    // fp32 W stage [65536,133120); dead before scr use
#define RED_OFF   0        // 256 floats in xrm region during phase 0 only
#define LDS_BYTES 133120
#define SROW 132           // stage row pitch in floats (528B = 16B mod 128B)

__device__ __forceinline__ unsigned short f2bf(float f) {
  unsigned u = __float_as_uint(f);
  return (unsigned short)((u + 0x7FFFu + ((u >> 16) & 1u)) >> 16);  // RNE
}
__device__ __forceinline__ float bf2f(unsigned short h) {
  return __uint_as_float(((unsigned)h) << 16);
}
__device__ __forceinline__ f32x16 zero16() {
  f32x16 z;
#pragma unroll
  for (int i = 0; i < 16; ++i) z[i] = 0.0f;
  return z;
}
// XOR swizzle in a [R][128] bf16 buffer: 8-elem granule g -> g ^ (R&15).
__device__ __forceinline__ int swz8(int R, int k0) {  // k0 % 8 == 0
  return R * 128 + (((k0 >> 3) ^ (R & 15)) << 3);
}
__device__ __forceinline__ int swz4(int R, int c0) {  // c0 % 4 == 0
  return R * 128 + ((((c0 >> 3) ^ (R & 15)) << 3) | (c0 & 7));
}
__device__ __forceinline__ int swz1(int R, int c) {
  return R * 128 + ((((c >> 3) ^ (R & 15)) << 3) | (c & 7));
}

__global__ void __launch_bounds__(1024, 4)
ns_inverse_kernel(const float* __restrict__ Wglob, const int* __restrict__ nIt,
                  float* __restrict__ outglob) {
  extern __shared__ char lds[];
  unsigned short* xrm = (unsigned short*)(lds + XRM_OFF);
  unsigned short* xcm = (unsigned short*)(lds + XCM_OFF);
  unsigned short* scr = (unsigned short*)(lds + SCR_OFF);
  float* stage = (float*)(lds + STAGE_OFF);
  float* red   = (float*)(lds + RED_OFF);

  const int b = blockIdx.x;
  const float* Wg = Wglob + (size_t)b * (NN * NN);
  float* outg = outglob + (size_t)b * (NN * NN);
  const int t = threadIdx.x;      // 0..1023
  const int lane = t & 63;
  const int wv = t >> 6;          // 0..15
  const int l31 = lane & 31;
  const int half = lane >> 5;
  const int s = wv & 3;           // strip: W rows (mm1 A) / X' rows (mm2 B, epi)
  const int v = wv >> 2;          // band: T cols / X' cols (mm2 A, epi)
  const int niters = nIt[0];

  // ---- phase 0: stage W fp32 into padded-pitch LDS (only global read) ----
  {
    const f32x4* src = (const f32x4*)Wg;
#pragma unroll
    for (int i = 0; i < 4; ++i) {
      int idx = t + 1024 * i;         // f32x4 index, 4096 total
      int r = idx >> 5, cp = idx & 31;
      f32x4 val = src[idx];
      *(f32x4*)(stage + r * SROW + 4 * cp) = val;
    }
  }
  __syncthreads();

  // ---- norms (red lives in xrm region; xrm filled later) ----
  if (t < 128) {            // row sums (rotated start)
    float ssum = 0.f;
    for (int jj = 0; jj < NN; ++jj) { int j = (jj + t) & 127; ssum += fabsf(stage[t * SROW + j]); }
    red[t] = ssum;
  } else if (t < 256) {     // col sums
    int c = t - 128;
    float ssum = 0.f;
    for (int i = 0; i < NN; ++i) ssum += fabsf(stage[i * SROW + c]);
    red[128 + c] = ssum;
  }
  __syncthreads();
  float ninf = 0.f, n1 = 0.f;
  for (int i = 0; i < 128; ++i) {   // broadcast reads (same addr across lanes)
    ninf = fmaxf(ninf, red[i]);
    n1   = fmaxf(n1,   red[128 + i]);
  }
  const float scale = 1.0f / (n1 * ninf);
  __syncthreads();   // everyone has scale; red region may be overwritten now

  // ---- W row fragments to registers (bf16(W), identical bits to R6 wrm) ----
  const int pX = 32 * s + l31;    // lane-owned W row / X/X' row
  bf16x8 wfrag[8];
#pragma unroll
  for (int ks = 0; ks < 8; ++ks) {
    const float* src = stage + pX * SROW + 16 * ks + 8 * half;
    f32x4 f0 = *(const f32x4*)(src);
    f32x4 f1 = *(const f32x4*)(src + 4);
    bf16x8 wb;
#pragma unroll
    for (int e = 0; e < 4; ++e) {
      wb[e]     = (short)f2bf(f0[e]);
      wb[4 + e] = (short)f2bf(f1[e]);
    }
    wfrag[ks] = wb;
  }

  // ---- fills from stage ----
  // xcm row r = X0 col r = W row r * scale
  {
    const int r = t >> 3;
    const int c0 = (t & 7) * 16;
#pragma unroll
    for (int h = 0; h < 4; ++h) {
      f32x4 a = *(const f32x4*)(stage + r * SROW + c0 + 4 * h);
      us4 hx;
#pragma unroll
      for (int i = 0; i < 4; ++i) hx[i] = f2bf(a[i] * scale);
      *(us4*)(xcm + swz4(r, c0 + 4 * h)) = hx;
    }
  }
  // xrm row r = X0 row r = W col r * scale (LDS transpose from stage)
  {
    const int r = t & 127;
    const int kc = (t >> 7) * 16;
#pragma unroll
    for (int j4 = 0; j4 < 4; ++j4) {
      int c0 = kc + 4 * j4;
      us4 h4;
#pragma unroll
      for (int i = 0; i < 4; ++i) h4[i] = f2bf(stage[(c0 + i) * SROW + r] * scale);
      *(us4*)(xrm + swz4(r, c0)) = h4;
    }
  }
  __syncthreads();   // stage dead from here; scr region free

  // ---------------- iterations: X' = 2X - X(WX) ----------------
  const int rv = 32 * v + l31;    // lane-owned xcm/scr row (= T col = X' col band)
  for (int it = 0; it < niters; ++it) {
    const bool last = (it == niters - 1);

    // ---- mm1: T tile rows [32s..), cols [32v..): A=wfrag (regs), B=xcm ----
    bf16x8 xb[8];   // prefetch of mm2's B operand (xrm rows; stable here)
    {
      f32x16 tt = zero16();
#pragma unroll
      for (int ks = 0; ks < 8; ++ks) {
        int k0 = ks * 16 + half * 8;
        bf16x8 bv = *(const bf16x8*)(xcm + swz8(rv, k0));
        tt = __builtin_amdgcn_mfma_f32_32x32x16_bf16(wfrag[ks], bv, tt, 0, 0, 0);
      }
#pragma unroll
      for (int ks = 0; ks < 8; ++ks) {
        int k0 = ks * 16 + half * 8;
        xb[ks] = *(const bf16x8*)(xrm + swz8(pX, k0));
      }
      // write T tile into scr (T col-major): scr row rv, cols = T rows strip s
#pragma unroll
      for (int q = 0; q < 4; ++q) {
        us4 h4;
#pragma unroll
        for (int i = 0; i < 4; ++i) h4[i] = f2bf(tt[4 * q + i]);
        *(us4*)(scr + swz4(rv, 32 * s + 8 * q + 4 * half)) = h4;
      }
    }
    __syncthreads();   // B1: full T assembled

    // ---- mm2: (X@T)^T tile rows [32v..) (X' cols), cols [32s..) (X' rows) ----
    f32x16 acc = zero16();
#pragma unroll
    for (int ks = 0; ks < 8; ++ks) {
      int k0 = ks * 16 + half * 8;
      bf16x8 av = *(const bf16x8*)(scr + swz8(rv, k0));   // T col-major row
      acc = __builtin_amdgcn_mfma_f32_32x32x16_bf16(av, xb[ks], acc, 0, 0, 0);
    }
    __syncthreads();   // B2: all scr + xrm reads complete before overwrite

    // ---- epilogue: X'[pX][32v + m] = 2X - (X@T) ----
#pragma unroll
    for (int q = 0; q < 4; ++q) {
      int c0m = 32 * v + 8 * q + 4 * half;
      int offr = swz4(pX, c0m);
      us4 xh4 = *(const us4*)(xrm + offr);
      f32x4 vv;
#pragma unroll
      for (int i = 0; i < 4; ++i)
        vv[i] = 2.0f * bf2f(xh4[i]) - acc[4 * q + i];
      if (last) {
        *(f32x4*)(outg + pX * NN + c0m) = vv;
      } else {
        us4 h4;
#pragma unroll
        for (int i = 0; i < 4; ++i) {
          unsigned short hh = f2bf(vv[i]);
          h4[i] = hh;
          xcm[swz1(c0m + i, pX)] = hh;     // X' col-major
        }
        *(us4*)(xrm + offr) = h4;          // X' row-major
      }
    }
    __syncthreads();   // B3: X' committed before next mm1
  }
}

extern "C" void kernel_launch(void* const* d_in, const int* in_sizes, int n_in,
                              void* d_out, int out_size, void* d_ws, size_t ws_size,
                              hipStream_t stream) {
  const float* W = (const float*)d_in[0];
  const int* nIt = (const int*)d_in[1];
  float* out = (float*)d_out;
  const int nmat = in_sizes[0] / (NN * NN);   // 1024

  hipFuncSetAttribute((const void*)ns_inverse_kernel,
                      hipFuncAttributeMaxDynamicSharedMemorySize, LDS_BYTES);
  ns_inverse_kernel<<<nmat, 1024, LDS_BYTES, stream>>>(W, nIt, out);
}